// Round 1
// 1158.832 us; speedup vs baseline: 1.0345x; 1.0345x over previous
//
#include <hip/hip_runtime.h>

#define NUM_C 1000
#define DIM 128
#define MARGIN 0.1f
#define SPLIT 8            // blocks per class in k_main

// ---------------- workspace layout ----------------
// [0      .. 4096)      counts  (u32[1024])
// [4096   .. 8192)      offsets (u32[1024])
// [8192   .. 12288)     cursor  (u32[1024])
// [16384  .. 528384)    diffsum (f32[NUM_C*DIM] = 512000 B)
// [532480 .. )          perm    (u32[N])

__global__ void k_init(unsigned* __restrict__ counts, float* __restrict__ diffsum,
                       float* __restrict__ out, int out_n) {
    int idx = blockIdx.x * blockDim.x + threadIdx.x;
    int stride = gridDim.x * blockDim.x;
    if (idx < 1024) counts[idx] = 0u;
    for (int i = idx; i < NUM_C * DIM; i += stride) diffsum[i] = 0.0f;
    if (idx < out_n) out[idx] = 0.0f;
}

__global__ void k_hist(const int* __restrict__ label, unsigned* __restrict__ counts, int n) {
    __shared__ unsigned h[NUM_C];
    for (int i = threadIdx.x; i < NUM_C; i += blockDim.x) h[i] = 0u;
    __syncthreads();
    int idx = blockIdx.x * blockDim.x + threadIdx.x;
    int stride = gridDim.x * blockDim.x;
    for (int i = idx; i < n; i += stride) atomicAdd(&h[label[i]], 1u);
    __syncthreads();
    for (int i = threadIdx.x; i < NUM_C; i += blockDim.x) {
        unsigned v = h[i];
        if (v) atomicAdd(&counts[i], v);
    }
}

// single block, 1024 threads: exclusive scan of counts -> offsets, cursor
__global__ void k_scan(const unsigned* __restrict__ counts,
                       unsigned* __restrict__ offsets,
                       unsigned* __restrict__ cursor) {
    __shared__ unsigned s[1024];
    int t = threadIdx.x;
    unsigned v = (t < NUM_C) ? counts[t] : 0u;
    s[t] = v;
    __syncthreads();
    for (int off = 1; off < 1024; off <<= 1) {
        unsigned x = (t >= off) ? s[t - off] : 0u;
        __syncthreads();
        s[t] += x;
        __syncthreads();
    }
    if (t < NUM_C) {
        unsigned e = s[t] - v;   // exclusive
        offsets[t] = e;
        cursor[t] = e;
    }
}

__global__ void k_scatter(const int* __restrict__ label,
                          unsigned* __restrict__ cursor,
                          unsigned* __restrict__ perm, int n) {
    int idx = blockIdx.x * blockDim.x + threadIdx.x;
    int stride = gridDim.x * blockDim.x;
    for (int i = idx; i < n; i += stride) {
        int c = label[i];
        unsigned p = atomicAdd(&cursor[c], 1u);
        perm[p] = (unsigned)i;
    }
}

// SPLIT blocks per class, 256 threads = 4 waves each.
// Each wave processes 2 rows per body (32-lane groups, float4/lane = 16B loads).
// Block-partial diff vector is atomically accumulated into diffsum[c][128].
__launch_bounds__(256)
__global__ void k_main(const float* __restrict__ f1, const float* __restrict__ f2,
                       const unsigned* __restrict__ offsets,
                       const unsigned* __restrict__ counts,
                       const unsigned* __restrict__ perm,
                       float* __restrict__ diffsum) {
    const int c   = blockIdx.x / SPLIT;
    const int sub = blockIdx.x % SPLIT;
    const unsigned start = offsets[c];
    const unsigned cnt = counts[c];
    const int wave = threadIdx.x >> 6;
    const int lane = threadIdx.x & 63;
    const int g    = lane >> 5;          // which row of the pair this half-wave owns
    const int lg   = lane & 31;          // lane within 32-group (covers 4 dims)
    const unsigned slot = (unsigned)(sub * 4 + wave);   // 0..31 slots per class

    float4 acc = make_float4(0.f, 0.f, 0.f, 0.f);

    auto body = [&](unsigned base) {
        unsigned rr = base + (unsigned)g;      // row index within the class
        bool act = rr < cnt;
        float4 v1 = make_float4(0.f, 0.f, 0.f, 0.f);
        float4 v2 = make_float4(0.f, 0.f, 0.f, 0.f);
        if (act) {
            unsigned row = perm[start + rr];   // broadcast per 32-group
            const float4* p1 = (const float4*)(f1 + (size_t)row * DIM);
            const float4* p2 = (const float4*)(f2 + (size_t)row * DIM);
            v1 = p1[lg];
            v2 = p2[lg];
        }
        float s1 = v1.x * v1.x + v1.y * v1.y + v1.z * v1.z + v1.w * v1.w;
        float s2 = v2.x * v2.x + v2.y * v2.y + v2.z * v2.z + v2.w * v2.w;
        #pragma unroll
        for (int off = 16; off; off >>= 1) {   // reduce within the 32-lane group
            s1 += __shfl_xor(s1, off);
            s2 += __shfl_xor(s2, off);
        }
        float i1 = act ? (1.0f / sqrtf(s1)) : 0.0f;
        float i2 = act ? (1.0f / sqrtf(s2)) : 0.0f;
        acc.x += v1.x * i1 - v2.x * i2;
        acc.y += v1.y * i1 - v2.y * i2;
        acc.z += v1.z * i1 - v2.z * i2;
        acc.w += v1.w * i1 - v2.w * i2;
    };

    // slot covers class rows {2*slot + 64*k, 2*slot + 64*k + 1}; unroll-2 for ILP
    for (unsigned base = 2u * slot; base < cnt; base += 128u) {
        body(base);
        body(base + 64u);     // self-guarded
    }

    // fold the two 32-groups together (they hold the same dims, different rows)
    acc.x += __shfl_xor(acc.x, 32);
    acc.y += __shfl_xor(acc.y, 32);
    acc.z += __shfl_xor(acc.z, 32);
    acc.w += __shfl_xor(acc.w, 32);

    __shared__ float lds[4][DIM];
    if (lane < 32) *(float4*)&lds[wave][lg * 4] = acc;
    __syncthreads();

    int d = threadIdx.x;
    if (d < DIM) {
        float v = lds[0][d] + lds[1][d] + lds[2][d] + lds[3][d];
        atomicAdd(&diffsum[c * DIM + d], v);
    }
}

// one block (1 wave) per class: hinge of ||diff/denom||^2
__launch_bounds__(64)
__global__ void k_final(const float* __restrict__ diffsum,
                        const unsigned* __restrict__ counts,
                        float* __restrict__ out) {
    int c = blockIdx.x;
    int lane = threadIdx.x;
    unsigned cnt = counts[c];
    float inv = 1.0f / fmaxf((float)cnt, 1.0f);
    float x0 = diffsum[c * DIM + lane] * inv;
    float x1 = diffsum[c * DIM + 64 + lane] * inv;
    float sq = x0 * x0 + x1 * x1;
    #pragma unroll
    for (int off = 32; off; off >>= 1) sq += __shfl_xor(sq, off);
    if (lane == 0 && cnt > 0u) {
        float h = sq - MARGIN;
        if (h > 0.0f) atomicAdd(out, h);
    }
}

extern "C" void kernel_launch(void* const* d_in, const int* in_sizes, int n_in,
                              void* d_out, int out_size, void* d_ws, size_t ws_size,
                              hipStream_t stream) {
    const float* feat1 = (const float*)d_in[0];
    const float* feat2 = (const float*)d_in[1];
    const int* label = (const int*)d_in[2];
    const int n = in_sizes[2];                 // number of rows

    char* ws = (char*)d_ws;
    unsigned* counts  = (unsigned*)(ws + 0);
    unsigned* offsets = (unsigned*)(ws + 4096);
    unsigned* cursor  = (unsigned*)(ws + 8192);
    float*    diffsum = (float*)(ws + 16384);
    unsigned* perm    = (unsigned*)(ws + 532480);
    float* out = (float*)d_out;

    k_init<<<64, 256, 0, stream>>>(counts, diffsum, out, out_size);
    k_hist<<<256, 256, 0, stream>>>(label, counts, n);
    k_scan<<<1, 1024, 0, stream>>>(counts, offsets, cursor);
    k_scatter<<<256, 256, 0, stream>>>(label, cursor, perm, n);
    k_main<<<NUM_C * SPLIT, 256, 0, stream>>>(feat1, feat2, offsets, counts, perm, diffsum);
    k_final<<<NUM_C, 64, 0, stream>>>(diffsum, counts, out);
}